// Round 7
// baseline (310.655 us; speedup 1.0000x reference)
//
#include <hip/hip_runtime.h>
#include <cstdint>

// N=4096 windows, T=33, C=96, H=6, HD=16.
// ws layout v3:
//   qf  : fp32 q[n][h][t][d]              4096*3168 floats  = 51.9 MB
//         (attn overwrites each window's q region with its output, [t][c] fp32)
//   kvh : bf16 {k,v}[n][s][h][t][d]       4096*6336 ushorts = 51.9 MB
//         (dead after attn; conv_w_proj stashes proj_w B-fragments at its start)
// GEMMs: MFMA 16x16x32 bf16 split-precision (hi+lo): C = AhBh + AlBh + AhBl.
// Attn v6: K staged to LDS as fp32 (exact widen), V bf16 in LDS (inline
// unpack in PV). 31.3 KB LDS. v5 bug fixed: V slab is 396 uint4s (not 198).

static constexpr int NWIN = 4096;
static constexpr int MROWS = NWIN * 33;          // 135168 = 1056*128
static constexpr float SCALE = 0.25f;            // HD^-0.5

using short8 = __attribute__((ext_vector_type(8))) short;
using f32x4  = __attribute__((ext_vector_type(4))) float;

__device__ __forceinline__ unsigned short f2bf(float f) {
  unsigned u = __float_as_uint(f);
  u += 0x7fffu + ((u >> 16) & 1u);
  return (unsigned short)(u >> 16);
}
__device__ __forceinline__ float bf2f(unsigned short h) {
  return __uint_as_float(((unsigned)h) << 16);
}
__device__ __forceinline__ float bflo(unsigned u) { return __uint_as_float(u << 16); }
__device__ __forceinline__ float bfhi(unsigned u) { return __uint_as_float(u & 0xffff0000u); }
__device__ __forceinline__ float dot4(const float4 a, const float4 b) {
  return a.x*b.x + a.y*b.y + a.z*b.z + a.w*b.w;
}

// ---------------- K0: qkv_w -> B-fragments in d_out ----------------
__global__ __launch_bounds__(256) void conv_w_qkv(
    const float* __restrict__ W, unsigned* __restrict__ frag) {
  const int fp = blockIdx.x;                     // 108 = 3 ksteps*18 cf*2 hl
  const int kstep = fp / 36;
  const int r = fp - kstep*36;
  const int cf = r >> 1, hl = r & 1;
  const int t = threadIdx.x, lane = t >> 2, d = t & 3;
  const int k = kstep*32 + (lane >> 4)*8 + d*2;
  const int n = cf*16 + (lane & 15);
  float w0 = W[k*288 + n], w1 = W[(k+1)*288 + n];
  if (hl) { w0 -= bf2f(f2bf(w0)); w1 -= bf2f(f2bf(w1)); }
  frag[fp*256 + t] = (unsigned)f2bf(w0) | ((unsigned)f2bf(w1) << 16);
}

// ---------------- K2b: proj_w -> B-fragments at start of (dead) kvh ----
__global__ __launch_bounds__(256) void conv_w_proj(
    const float* __restrict__ W, unsigned* __restrict__ frag) {
  const int fp = blockIdx.x;                     // 36 = 3 ksteps*6 cf*2 hl
  const int kstep = fp / 12;
  const int r = fp - kstep*12;
  const int cf = r >> 1, hl = r & 1;
  const int t = threadIdx.x, lane = t >> 2, d = t & 3;
  const int k = kstep*32 + (lane >> 4)*8 + d*2;
  const int n = cf*16 + (lane & 15);
  float w0 = W[k*96 + n], w1 = W[(k+1)*96 + n];
  if (hl) { w0 -= bf2f(f2bf(w0)); w1 -= bf2f(f2bf(w1)); }
  frag[fp*256 + t] = (unsigned)f2bf(w0) | ((unsigned)f2bf(w1) << 16);
}

// ---------------- K1: QKV projection, split-bf16 MFMA ----------------
// grid (1056, 3), block 256 (4 waves). s: 0=q (fp32 out), 1=k, 2=v (bf16 out).
__global__ __launch_bounds__(256) void qkv_mfma(
    const float* __restrict__ A, const unsigned* __restrict__ frag,
    const float* __restrict__ bias, float* __restrict__ qf,
    unsigned short* __restrict__ kvh) {
  __shared__ __align__(16) unsigned short sAh[128*104];
  __shared__ __align__(16) unsigned short sAl[128*104];
  const int tid = threadIdx.x;
  const int w = tid >> 6, l = tid & 63;
  const int m0 = blockIdx.x * 128;
  const int s = blockIdx.y;
  for (int idx = tid; idx < 3072; idx += 256) {
    const int row = idx / 24, q = idx - row*24;
    const float4 v = *(const float4*)(A + (size_t)(m0+row)*96 + q*4);
    ushort4 hv, lv;
    hv.x = f2bf(v.x); hv.y = f2bf(v.y); hv.z = f2bf(v.z); hv.w = f2bf(v.w);
    lv.x = f2bf(v.x - bf2f(hv.x)); lv.y = f2bf(v.y - bf2f(hv.y));
    lv.z = f2bf(v.z - bf2f(hv.z)); lv.w = f2bf(v.w - bf2f(hv.w));
    *(ushort4*)&sAh[row*104 + q*4] = hv;
    *(ushort4*)&sAl[row*104 + q*4] = lv;
  }
  __syncthreads();
  f32x4 acc[2][6];
  #pragma unroll
  for (int rf = 0; rf < 2; ++rf)
    #pragma unroll
    for (int cf = 0; cf < 6; ++cf) acc[rf][cf] = (f32x4){0.f,0.f,0.f,0.f};

  #pragma unroll
  for (int kstep = 0; kstep < 3; ++kstep) {
    short8 bh[6], bl[6];
    #pragma unroll
    for (int cf = 0; cf < 6; ++cf) {
      const int fp = (kstep*18 + s*6 + cf)*2;
      bh[cf] = *(const short8*)((const char*)frag + (size_t)fp*1024 + l*16);
      bl[cf] = *(const short8*)((const char*)frag + (size_t)fp*1024 + 1024 + l*16);
    }
    #pragma unroll
    for (int rf = 0; rf < 2; ++rf) {
      const int row = w*32 + rf*16 + (l & 15);
      const int off = row*104 + kstep*32 + (l >> 4)*8;
      const short8 ah = *(const short8*)&sAh[off];
      const short8 al = *(const short8*)&sAl[off];
      #pragma unroll
      for (int cf = 0; cf < 6; ++cf) {
        acc[rf][cf] = __builtin_amdgcn_mfma_f32_16x16x32_bf16(ah, bh[cf], acc[rf][cf], 0,0,0);
        acc[rf][cf] = __builtin_amdgcn_mfma_f32_16x16x32_bf16(al, bh[cf], acc[rf][cf], 0,0,0);
        acc[rf][cf] = __builtin_amdgcn_mfma_f32_16x16x32_bf16(ah, bl[cf], acc[rf][cf], 0,0,0);
      }
    }
  }
  const int col = l & 15;
  if (s == 0) {
    #pragma unroll
    for (int cf = 0; cf < 6; ++cf) {
      const float bv = bias[cf*16 + col];
      #pragma unroll
      for (int rf = 0; rf < 2; ++rf)
        #pragma unroll
        for (int r = 0; r < 4; ++r) {
          const int m = m0 + w*32 + rf*16 + (l >> 4)*4 + r;
          const int n = m / 33, t = m - n*33;
          qf[(size_t)n*3168 + cf*528 + t*16 + col] = (acc[rf][cf][r] + bv)*SCALE;
        }
    }
  } else {
    unsigned short* kvs = kvh + (size_t)(s-1)*3168;
    #pragma unroll
    for (int cf = 0; cf < 6; ++cf) {
      const float bv = bias[s*96 + cf*16 + col];
      #pragma unroll
      for (int rf = 0; rf < 2; ++rf)
        #pragma unroll
        for (int r = 0; r < 4; ++r) {
          const int m = m0 + w*32 + rf*16 + (l >> 4)*4 + r;
          const int n = m / 33, t = m - n*33;
          kvs[(size_t)n*6336 + cf*528 + t*16 + col] = f2bf(acc[rf][cf][r] + bv);
        }
    }
  }
}

// ---------------- K2: per-window attention (v6) ----------------
// grid 4096, block 256; thread = (head,row), 198 active.
// LDS 31.3 KB: K fp32 (staged convert), V bf16 (inline unpack), mask/relP/rpe.
__global__ __launch_bounds__(256) void attn_kernel(
    float* __restrict__ qf, const unsigned short* __restrict__ kvh,
    const int* __restrict__ rel, const float* __restrict__ mask,
    const float* __restrict__ rpet) {
  __shared__ __align__(16) float sKf[3168];           // 12672 B
  __shared__ __align__(16) unsigned short sVh[3168];  //  6336 B
  __shared__ float sMask[1089];                       //  4356 B
  __shared__ unsigned sRelP[1056];                    //  4224 B
  __shared__ float sRPE[918];                         //  3672 B
  const int tid = threadIdx.x;
  const int n = blockIdx.x;
  const uint4* kvb = (const uint4*)(kvh + (size_t)n*6336);
  // K: 3168 bf16 = 396 uint4 -> fp32 LDS (exact widen)
  for (int idx = tid; idx < 396; idx += 256) {
    const uint4 u = kvb[idx];
    float4 a, b;
    a.x = bflo(u.x); a.y = bfhi(u.x); a.z = bflo(u.y); a.w = bfhi(u.y);
    b.x = bflo(u.z); b.y = bfhi(u.z); b.z = bflo(u.w); b.w = bfhi(u.w);
    *(float4*)&sKf[idx*8]     = a;
    *(float4*)&sKf[idx*8 + 4] = b;
  }
  // V: raw bf16 copy — V slab is 3168 ushorts = 396 uint4 (v5 bug: used 198)
  for (int idx = tid; idx < 396; idx += 256)
    ((uint4*)sVh)[idx] = kvb[396 + idx];
  {
    const int* rb = rel + (size_t)n*3072;
    for (int p = tid; p < 1024; p += 256) {
      const int b = p*3;
      sRelP[(p >> 5)*33 + (p & 31)] =
          (unsigned)rb[b] | ((unsigned)rb[b+1] << 8) | ((unsigned)rb[b+2] << 16);
    }
  }
  for (int idx = tid; idx < 1089; idx += 256)
    sMask[idx] = mask[(size_t)n*1089 + idx];
  for (int idx = tid; idx < 918; idx += 256)
    sRPE[idx] = rpet[idx];

  float4 q0, q1, q2, q3;
  int h = 0, i = 0;
  if (tid < 198) {
    h = tid / 33; i = tid - h*33;
    const float4* qb = (const float4*)(qf + (size_t)n*3168 + h*528 + i*16);
    q0 = qb[0]; q1 = qb[1]; q2 = qb[2]; q3 = qb[3];   // q read BEFORE barrier
  }
  __syncthreads();
  if (tid < 198) {
    const float* rph = sRPE + h;
    float p[33];
    float mx = -3.4e38f;
    #pragma unroll
    for (int j = 0; j < 33; ++j) {
      const float4* kr = (const float4*)&sKf[(h*33 + j)*16];
      float lo = dot4(q0,kr[0]) + dot4(q1,kr[1]) + dot4(q2,kr[2]) + dot4(q3,kr[3]);
      lo += sMask[i*33 + j];
      if (i > 0 && j > 0) {
        const unsigned pk = sRelP[(i-1)*33 + (j-1)];
        lo += rph[(pk & 0xffu)*6]
            + rph[((pk >> 8) & 0xffu)*6 + 306]
            + rph[((pk >> 16) & 0xffu)*6 + 612];
      }
      p[j] = lo;
      mx = fmaxf(mx, lo);
    }
    float ssum = 0.f;
    #pragma unroll
    for (int j = 0; j < 33; ++j) { p[j] = __expf(p[j] - mx); ssum += p[j]; }
    const float inv = 1.0f / ssum;
    float4 o0 = make_float4(0.f,0.f,0.f,0.f), o1 = o0, o2 = o0, o3 = o0;
    #pragma unroll
    for (int j = 0; j < 33; ++j) {
      const float pj = p[j];
      const uint4 u0 = *(const uint4*)&sVh[(h*33 + j)*16];
      const uint4 u1 = *(const uint4*)&sVh[(h*33 + j)*16 + 8];
      o0.x = fmaf(pj, bflo(u0.x), o0.x); o0.y = fmaf(pj, bfhi(u0.x), o0.y);
      o0.z = fmaf(pj, bflo(u0.y), o0.z); o0.w = fmaf(pj, bfhi(u0.y), o0.w);
      o1.x = fmaf(pj, bflo(u0.z), o1.x); o1.y = fmaf(pj, bfhi(u0.z), o1.y);
      o1.z = fmaf(pj, bflo(u0.w), o1.z); o1.w = fmaf(pj, bfhi(u0.w), o1.w);
      o2.x = fmaf(pj, bflo(u1.x), o2.x); o2.y = fmaf(pj, bfhi(u1.x), o2.y);
      o2.z = fmaf(pj, bflo(u1.y), o2.z); o2.w = fmaf(pj, bfhi(u1.y), o2.w);
      o3.x = fmaf(pj, bflo(u1.z), o3.x); o3.y = fmaf(pj, bfhi(u1.z), o3.y);
      o3.z = fmaf(pj, bflo(u1.w), o3.z); o3.w = fmaf(pj, bfhi(u1.w), o3.w);
    }
    o0.x*=inv; o0.y*=inv; o0.z*=inv; o0.w*=inv;
    o1.x*=inv; o1.y*=inv; o1.z*=inv; o1.w*=inv;
    o2.x*=inv; o2.y*=inv; o2.z*=inv; o2.w*=inv;
    o3.x*=inv; o3.y*=inv; o3.z*=inv; o3.w*=inv;
    float* op = qf + (size_t)n*3168 + (size_t)i*96 + h*16;
    *(float4*)(op + 0)  = o0; *(float4*)(op + 4)  = o1;
    *(float4*)(op + 8)  = o2; *(float4*)(op + 12) = o3;
  }
}

// ---------------- K3: output projection, split-bf16 MFMA ----------------
// grid 1056, block 256. A = attn output in qf; B-frags at start of kvh.
__global__ __launch_bounds__(256) void proj_mfma(
    const float* __restrict__ qf, const unsigned* __restrict__ frag,
    const float* __restrict__ bias, float* __restrict__ out) {
  __shared__ __align__(16) unsigned short sAh[128*104];
  __shared__ __align__(16) unsigned short sAl[128*104];
  const int tid = threadIdx.x;
  const int w = tid >> 6, l = tid & 63;
  const int m0 = blockIdx.x * 128;
  for (int idx = tid; idx < 3072; idx += 256) {
    const int row = idx / 24, q = idx - row*24;
    const int m = m0 + row;
    const int n = m / 33, t = m - n*33;
    const float4 v = *(const float4*)(qf + (size_t)n*3168 + t*96 + q*4);
    ushort4 hv, lv;
    hv.x = f2bf(v.x); hv.y = f2bf(v.y); hv.z = f2bf(v.z); hv.w = f2bf(v.w);
    lv.x = f2bf(v.x - bf2f(hv.x)); lv.y = f2bf(v.y - bf2f(hv.y));
    lv.z = f2bf(v.z - bf2f(hv.z)); lv.w = f2bf(v.w - bf2f(hv.w));
    *(ushort4*)&sAh[row*104 + q*4] = hv;
    *(ushort4*)&sAl[row*104 + q*4] = lv;
  }
  __syncthreads();
  f32x4 acc[2][6];
  #pragma unroll
  for (int rf = 0; rf < 2; ++rf)
    #pragma unroll
    for (int cf = 0; cf < 6; ++cf) acc[rf][cf] = (f32x4){0.f,0.f,0.f,0.f};

  #pragma unroll
  for (int kstep = 0; kstep < 3; ++kstep) {
    short8 bh[6], bl[6];
    #pragma unroll
    for (int cf = 0; cf < 6; ++cf) {
      const int fph = kstep*12 + cf*2;
      bh[cf] = *(const short8*)(frag + fph*256 + l*4);
      bl[cf] = *(const short8*)(frag + (fph+1)*256 + l*4);
    }
    #pragma unroll
    for (int rf = 0; rf < 2; ++rf) {
      const int row = w*32 + rf*16 + (l & 15);
      const int off = row*104 + kstep*32 + (l >> 4)*8;
      const short8 ah = *(const short8*)&sAh[off];
      const short8 al = *(const short8*)&sAl[off];
      #pragma unroll
      for (int cf = 0; cf < 6; ++cf) {
        acc[rf][cf] = __builtin_amdgcn_mfma_f32_16x16x32_bf16(ah, bh[cf], acc[rf][cf], 0,0,0);
        acc[rf][cf] = __builtin_amdgcn_mfma_f32_16x16x32_bf16(al, bh[cf], acc[rf][cf], 0,0,0);
        acc[rf][cf] = __builtin_amdgcn_mfma_f32_16x16x32_bf16(ah, bl[cf], acc[rf][cf], 0,0,0);
      }
    }
  }
  const int col = l & 15;
  #pragma unroll
  for (int cf = 0; cf < 6; ++cf) {
    const float bv = bias[cf*16 + col];
    #pragma unroll
    for (int rf = 0; rf < 2; ++rf)
      #pragma unroll
      for (int r = 0; r < 4; ++r) {
        const int m = m0 + w*32 + rf*16 + (l >> 4)*4 + r;
        out[(size_t)m*96 + cf*16 + col] = acc[rf][cf][r] + bv;
      }
  }
}

extern "C" void kernel_launch(void* const* d_in, const int* in_sizes, int n_in,
                              void* d_out, int out_size, void* d_ws, size_t ws_size,
                              hipStream_t stream) {
  const float* data   = (const float*)d_in[0];
  const int*   rel    = (const int*)  d_in[1];
  const float* mask   = (const float*)d_in[2];
  const float* qkv_w  = (const float*)d_in[3];
  const float* qkv_b  = (const float*)d_in[4];
  const float* proj_w = (const float*)d_in[5];
  const float* proj_b = (const float*)d_in[6];
  const float* rpet   = (const float*)d_in[7];
  float* qf = (float*)d_ws;                              // 51.9 MB
  unsigned short* kvh = (unsigned short*)(qf + (size_t)NWIN*3168);  // 51.9 MB
  float* out = (float*)d_out;

  conv_w_qkv <<<dim3(108),         256, 0, stream>>>(qkv_w, (unsigned*)d_out);
  qkv_mfma   <<<dim3(MROWS/128,3), 256, 0, stream>>>(data, (const unsigned*)d_out, qkv_b, qf, kvh);
  attn_kernel<<<dim3(NWIN),        256, 0, stream>>>(qf, kvh, rel, mask, rpet);
  conv_w_proj<<<dim3(36),          256, 0, stream>>>(proj_w, (unsigned*)kvh);
  proj_mfma  <<<dim3(MROWS/128),   256, 0, stream>>>(qf, (const unsigned*)kvh, proj_b, out);
}

// Round 8
// 172.603 us; speedup vs baseline: 1.7998x; 1.7998x over previous
//
#include <hip/hip_runtime.h>
#include <cstdint>

// N=4096 windows, T=33, C=96, H=6, HD=16.
// ws layout v3:
//   qf  : fp32 q[n][h][t][d]              4096*3168 floats  = 51.9 MB
//         (attn overwrites each window's q region with its output, [t][c] fp32)
//   kvh : bf16 {k,v}[n][s][h][t][d]       4096*6336 ushorts = 51.9 MB
//         (dead after attn; conv_w_proj stashes proj_w B-fragments at its start)
// GEMMs: MFMA 16x16x32 bf16 split-precision (hi+lo): C = AhBh + AlBh + AhBl.
// Attn v7: BOTH K and V staged to LDS as fp32 (exact widen at stage time);
// inner loops are round-3's lean float4 dot4/axpy4 (64-VGPR-proven).
// LDS 37.6 KB -> 4 blocks/CU. Lesson from v4/v6: bf16 unpack inside the
// unrolled QK/PV loops explodes VGPR (132-136); unpack at staging is free.

static constexpr int NWIN = 4096;
static constexpr int MROWS = NWIN * 33;          // 135168 = 1056*128
static constexpr float SCALE = 0.25f;            // HD^-0.5

using short8 = __attribute__((ext_vector_type(8))) short;
using f32x4  = __attribute__((ext_vector_type(4))) float;

__device__ __forceinline__ unsigned short f2bf(float f) {
  unsigned u = __float_as_uint(f);
  u += 0x7fffu + ((u >> 16) & 1u);
  return (unsigned short)(u >> 16);
}
__device__ __forceinline__ float bf2f(unsigned short h) {
  return __uint_as_float(((unsigned)h) << 16);
}
__device__ __forceinline__ float bflo(unsigned u) { return __uint_as_float(u << 16); }
__device__ __forceinline__ float bfhi(unsigned u) { return __uint_as_float(u & 0xffff0000u); }
__device__ __forceinline__ float dot4(const float4 a, const float4 b) {
  return a.x*b.x + a.y*b.y + a.z*b.z + a.w*b.w;
}
__device__ __forceinline__ void axpy4(float4& o, const float a, const float4 v) {
  o.x += a*v.x; o.y += a*v.y; o.z += a*v.z; o.w += a*v.w;
}

// ---------------- K0: qkv_w -> B-fragments in d_out ----------------
__global__ __launch_bounds__(256) void conv_w_qkv(
    const float* __restrict__ W, unsigned* __restrict__ frag) {
  const int fp = blockIdx.x;                     // 108 = 3 ksteps*18 cf*2 hl
  const int kstep = fp / 36;
  const int r = fp - kstep*36;
  const int cf = r >> 1, hl = r & 1;
  const int t = threadIdx.x, lane = t >> 2, d = t & 3;
  const int k = kstep*32 + (lane >> 4)*8 + d*2;
  const int n = cf*16 + (lane & 15);
  float w0 = W[k*288 + n], w1 = W[(k+1)*288 + n];
  if (hl) { w0 -= bf2f(f2bf(w0)); w1 -= bf2f(f2bf(w1)); }
  frag[fp*256 + t] = (unsigned)f2bf(w0) | ((unsigned)f2bf(w1) << 16);
}

// ---------------- K2b: proj_w -> B-fragments at start of (dead) kvh ----
__global__ __launch_bounds__(256) void conv_w_proj(
    const float* __restrict__ W, unsigned* __restrict__ frag) {
  const int fp = blockIdx.x;                     // 36 = 3 ksteps*6 cf*2 hl
  const int kstep = fp / 12;
  const int r = fp - kstep*12;
  const int cf = r >> 1, hl = r & 1;
  const int t = threadIdx.x, lane = t >> 2, d = t & 3;
  const int k = kstep*32 + (lane >> 4)*8 + d*2;
  const int n = cf*16 + (lane & 15);
  float w0 = W[k*96 + n], w1 = W[(k+1)*96 + n];
  if (hl) { w0 -= bf2f(f2bf(w0)); w1 -= bf2f(f2bf(w1)); }
  frag[fp*256 + t] = (unsigned)f2bf(w0) | ((unsigned)f2bf(w1) << 16);
}

// ---------------- K1: QKV projection, split-bf16 MFMA ----------------
// grid (1056, 3), block 256 (4 waves). s: 0=q (fp32 out), 1=k, 2=v (bf16 out).
__global__ __launch_bounds__(256) void qkv_mfma(
    const float* __restrict__ A, const unsigned* __restrict__ frag,
    const float* __restrict__ bias, float* __restrict__ qf,
    unsigned short* __restrict__ kvh) {
  __shared__ __align__(16) unsigned short sAh[128*104];
  __shared__ __align__(16) unsigned short sAl[128*104];
  const int tid = threadIdx.x;
  const int w = tid >> 6, l = tid & 63;
  const int m0 = blockIdx.x * 128;
  const int s = blockIdx.y;
  for (int idx = tid; idx < 3072; idx += 256) {
    const int row = idx / 24, q = idx - row*24;
    const float4 v = *(const float4*)(A + (size_t)(m0+row)*96 + q*4);
    ushort4 hv, lv;
    hv.x = f2bf(v.x); hv.y = f2bf(v.y); hv.z = f2bf(v.z); hv.w = f2bf(v.w);
    lv.x = f2bf(v.x - bf2f(hv.x)); lv.y = f2bf(v.y - bf2f(hv.y));
    lv.z = f2bf(v.z - bf2f(hv.z)); lv.w = f2bf(v.w - bf2f(hv.w));
    *(ushort4*)&sAh[row*104 + q*4] = hv;
    *(ushort4*)&sAl[row*104 + q*4] = lv;
  }
  __syncthreads();
  f32x4 acc[2][6];
  #pragma unroll
  for (int rf = 0; rf < 2; ++rf)
    #pragma unroll
    for (int cf = 0; cf < 6; ++cf) acc[rf][cf] = (f32x4){0.f,0.f,0.f,0.f};

  #pragma unroll
  for (int kstep = 0; kstep < 3; ++kstep) {
    short8 bh[6], bl[6];
    #pragma unroll
    for (int cf = 0; cf < 6; ++cf) {
      const int fp = (kstep*18 + s*6 + cf)*2;
      bh[cf] = *(const short8*)((const char*)frag + (size_t)fp*1024 + l*16);
      bl[cf] = *(const short8*)((const char*)frag + (size_t)fp*1024 + 1024 + l*16);
    }
    #pragma unroll
    for (int rf = 0; rf < 2; ++rf) {
      const int row = w*32 + rf*16 + (l & 15);
      const int off = row*104 + kstep*32 + (l >> 4)*8;
      const short8 ah = *(const short8*)&sAh[off];
      const short8 al = *(const short8*)&sAl[off];
      #pragma unroll
      for (int cf = 0; cf < 6; ++cf) {
        acc[rf][cf] = __builtin_amdgcn_mfma_f32_16x16x32_bf16(ah, bh[cf], acc[rf][cf], 0,0,0);
        acc[rf][cf] = __builtin_amdgcn_mfma_f32_16x16x32_bf16(al, bh[cf], acc[rf][cf], 0,0,0);
        acc[rf][cf] = __builtin_amdgcn_mfma_f32_16x16x32_bf16(ah, bl[cf], acc[rf][cf], 0,0,0);
      }
    }
  }
  const int col = l & 15;
  if (s == 0) {
    #pragma unroll
    for (int cf = 0; cf < 6; ++cf) {
      const float bv = bias[cf*16 + col];
      #pragma unroll
      for (int rf = 0; rf < 2; ++rf)
        #pragma unroll
        for (int r = 0; r < 4; ++r) {
          const int m = m0 + w*32 + rf*16 + (l >> 4)*4 + r;
          const int n = m / 33, t = m - n*33;
          qf[(size_t)n*3168 + cf*528 + t*16 + col] = (acc[rf][cf][r] + bv)*SCALE;
        }
    }
  } else {
    unsigned short* kvs = kvh + (size_t)(s-1)*3168;
    #pragma unroll
    for (int cf = 0; cf < 6; ++cf) {
      const float bv = bias[s*96 + cf*16 + col];
      #pragma unroll
      for (int rf = 0; rf < 2; ++rf)
        #pragma unroll
        for (int r = 0; r < 4; ++r) {
          const int m = m0 + w*32 + rf*16 + (l >> 4)*4 + r;
          const int n = m / 33, t = m - n*33;
          kvs[(size_t)n*6336 + cf*528 + t*16 + col] = f2bf(acc[rf][cf][r] + bv);
        }
    }
  }
}

// ---------------- K2: per-window attention (v7) ----------------
// grid 4096, block 256; thread = (head,row), 198 active.
// K and V both fp32 in LDS (widened at stage time). 37.6 KB LDS.
__global__ __launch_bounds__(256) void attn_kernel(
    float* __restrict__ qf, const unsigned short* __restrict__ kvh,
    const int* __restrict__ rel, const float* __restrict__ mask,
    const float* __restrict__ rpet) {
  __shared__ __align__(16) float sKf[3168];           // 12672 B
  __shared__ __align__(16) float sVf[3168];           // 12672 B
  __shared__ float sMask[1089];                       //  4356 B
  __shared__ unsigned sRelP[1056];                    //  4224 B
  __shared__ float sRPE[918];                         //  3672 B
  const int tid = threadIdx.x;
  const int n = blockIdx.x;
  const uint4* kvb = (const uint4*)(kvh + (size_t)n*6336);
  // K and V: 396 uint4 each, bf16 -> fp32 exact widen
  for (int idx = tid; idx < 396; idx += 256) {
    const uint4 u = kvb[idx];
    float4 a, b;
    a.x = bflo(u.x); a.y = bfhi(u.x); a.z = bflo(u.y); a.w = bfhi(u.y);
    b.x = bflo(u.z); b.y = bfhi(u.z); b.z = bflo(u.w); b.w = bfhi(u.w);
    *(float4*)&sKf[idx*8]     = a;
    *(float4*)&sKf[idx*8 + 4] = b;
    const uint4 w = kvb[396 + idx];
    float4 c, d;
    c.x = bflo(w.x); c.y = bfhi(w.x); c.z = bflo(w.y); c.w = bfhi(w.y);
    d.x = bflo(w.z); d.y = bfhi(w.z); d.z = bflo(w.w); d.w = bfhi(w.w);
    *(float4*)&sVf[idx*8]     = c;
    *(float4*)&sVf[idx*8 + 4] = d;
  }
  {
    const int* rb = rel + (size_t)n*3072;
    for (int p = tid; p < 1024; p += 256) {
      const int b = p*3;
      sRelP[(p >> 5)*33 + (p & 31)] =
          (unsigned)rb[b] | ((unsigned)rb[b+1] << 8) | ((unsigned)rb[b+2] << 16);
    }
  }
  for (int idx = tid; idx < 1089; idx += 256)
    sMask[idx] = mask[(size_t)n*1089 + idx];
  for (int idx = tid; idx < 918; idx += 256)
    sRPE[idx] = rpet[idx];

  float4 q0, q1, q2, q3;
  int h = 0, i = 0;
  if (tid < 198) {
    h = tid / 33; i = tid - h*33;
    const float4* qb = (const float4*)(qf + (size_t)n*3168 + h*528 + i*16);
    q0 = qb[0]; q1 = qb[1]; q2 = qb[2]; q3 = qb[3];   // q read BEFORE barrier
  }
  __syncthreads();
  if (tid < 198) {
    const float* rph = sRPE + h;
    float p[33];
    float mx = -3.4e38f;
    #pragma unroll
    for (int j = 0; j < 33; ++j) {
      const float4* kr = (const float4*)&sKf[(h*33 + j)*16];
      float lo = dot4(q0,kr[0]) + dot4(q1,kr[1]) + dot4(q2,kr[2]) + dot4(q3,kr[3]);
      lo += sMask[i*33 + j];
      if (i > 0 && j > 0) {
        const unsigned pk = sRelP[(i-1)*33 + (j-1)];
        lo += rph[(pk & 0xffu)*6]
            + rph[((pk >> 8) & 0xffu)*6 + 306]
            + rph[((pk >> 16) & 0xffu)*6 + 612];
      }
      p[j] = lo;
      mx = fmaxf(mx, lo);
    }
    float ssum = 0.f;
    #pragma unroll
    for (int j = 0; j < 33; ++j) { p[j] = __expf(p[j] - mx); ssum += p[j]; }
    const float inv = 1.0f / ssum;
    float4 o0 = make_float4(0.f,0.f,0.f,0.f), o1 = o0, o2 = o0, o3 = o0;
    #pragma unroll
    for (int j = 0; j < 33; ++j) {
      const float pj = p[j];
      const float4* vr = (const float4*)&sVf[(h*33 + j)*16];
      axpy4(o0, pj, vr[0]); axpy4(o1, pj, vr[1]);
      axpy4(o2, pj, vr[2]); axpy4(o3, pj, vr[3]);
    }
    o0.x*=inv; o0.y*=inv; o0.z*=inv; o0.w*=inv;
    o1.x*=inv; o1.y*=inv; o1.z*=inv; o1.w*=inv;
    o2.x*=inv; o2.y*=inv; o2.z*=inv; o2.w*=inv;
    o3.x*=inv; o3.y*=inv; o3.z*=inv; o3.w*=inv;
    float* op = qf + (size_t)n*3168 + (size_t)i*96 + h*16;
    *(float4*)(op + 0)  = o0; *(float4*)(op + 4)  = o1;
    *(float4*)(op + 8)  = o2; *(float4*)(op + 12) = o3;
  }
}

// ---------------- K3: output projection, split-bf16 MFMA ----------------
// grid 1056, block 256. A = attn output in qf; B-frags at start of kvh.
__global__ __launch_bounds__(256) void proj_mfma(
    const float* __restrict__ qf, const unsigned* __restrict__ frag,
    const float* __restrict__ bias, float* __restrict__ out) {
  __shared__ __align__(16) unsigned short sAh[128*104];
  __shared__ __align__(16) unsigned short sAl[128*104];
  const int tid = threadIdx.x;
  const int w = tid >> 6, l = tid & 63;
  const int m0 = blockIdx.x * 128;
  for (int idx = tid; idx < 3072; idx += 256) {
    const int row = idx / 24, q = idx - row*24;
    const int m = m0 + row;
    const int n = m / 33, t = m - n*33;
    const float4 v = *(const float4*)(qf + (size_t)n*3168 + t*96 + q*4);
    ushort4 hv, lv;
    hv.x = f2bf(v.x); hv.y = f2bf(v.y); hv.z = f2bf(v.z); hv.w = f2bf(v.w);
    lv.x = f2bf(v.x - bf2f(hv.x)); lv.y = f2bf(v.y - bf2f(hv.y));
    lv.z = f2bf(v.z - bf2f(hv.z)); lv.w = f2bf(v.w - bf2f(hv.w));
    *(ushort4*)&sAh[row*104 + q*4] = hv;
    *(ushort4*)&sAl[row*104 + q*4] = lv;
  }
  __syncthreads();
  f32x4 acc[2][6];
  #pragma unroll
  for (int rf = 0; rf < 2; ++rf)
    #pragma unroll
    for (int cf = 0; cf < 6; ++cf) acc[rf][cf] = (f32x4){0.f,0.f,0.f,0.f};

  #pragma unroll
  for (int kstep = 0; kstep < 3; ++kstep) {
    short8 bh[6], bl[6];
    #pragma unroll
    for (int cf = 0; cf < 6; ++cf) {
      const int fph = kstep*12 + cf*2;
      bh[cf] = *(const short8*)(frag + fph*256 + l*4);
      bl[cf] = *(const short8*)(frag + (fph+1)*256 + l*4);
    }
    #pragma unroll
    for (int rf = 0; rf < 2; ++rf) {
      const int row = w*32 + rf*16 + (l & 15);
      const int off = row*104 + kstep*32 + (l >> 4)*8;
      const short8 ah = *(const short8*)&sAh[off];
      const short8 al = *(const short8*)&sAl[off];
      #pragma unroll
      for (int cf = 0; cf < 6; ++cf) {
        acc[rf][cf] = __builtin_amdgcn_mfma_f32_16x16x32_bf16(ah, bh[cf], acc[rf][cf], 0,0,0);
        acc[rf][cf] = __builtin_amdgcn_mfma_f32_16x16x32_bf16(al, bh[cf], acc[rf][cf], 0,0,0);
        acc[rf][cf] = __builtin_amdgcn_mfma_f32_16x16x32_bf16(ah, bl[cf], acc[rf][cf], 0,0,0);
      }
    }
  }
  const int col = l & 15;
  #pragma unroll
  for (int cf = 0; cf < 6; ++cf) {
    const float bv = bias[cf*16 + col];
    #pragma unroll
    for (int rf = 0; rf < 2; ++rf)
      #pragma unroll
      for (int r = 0; r < 4; ++r) {
        const int m = m0 + w*32 + rf*16 + (l >> 4)*4 + r;
        out[(size_t)m*96 + cf*16 + col] = acc[rf][cf][r] + bv;
      }
  }
}

extern "C" void kernel_launch(void* const* d_in, const int* in_sizes, int n_in,
                              void* d_out, int out_size, void* d_ws, size_t ws_size,
                              hipStream_t stream) {
  const float* data   = (const float*)d_in[0];
  const int*   rel    = (const int*)  d_in[1];
  const float* mask   = (const float*)d_in[2];
  const float* qkv_w  = (const float*)d_in[3];
  const float* qkv_b  = (const float*)d_in[4];
  const float* proj_w = (const float*)d_in[5];
  const float* proj_b = (const float*)d_in[6];
  const float* rpet   = (const float*)d_in[7];
  float* qf = (float*)d_ws;                              // 51.9 MB
  unsigned short* kvh = (unsigned short*)(qf + (size_t)NWIN*3168);  // 51.9 MB
  float* out = (float*)d_out;

  conv_w_qkv <<<dim3(108),         256, 0, stream>>>(qkv_w, (unsigned*)d_out);
  qkv_mfma   <<<dim3(MROWS/128,3), 256, 0, stream>>>(data, (const unsigned*)d_out, qkv_b, qf, kvh);
  attn_kernel<<<dim3(NWIN),        256, 0, stream>>>(qf, kvh, rel, mask, rpet);
  conv_w_proj<<<dim3(36),          256, 0, stream>>>(proj_w, (unsigned*)kvh);
  proj_mfma  <<<dim3(MROWS/128),   256, 0, stream>>>(qf, (const unsigned*)kvh, proj_b, out);
}